// Round 6
// baseline (248.789 us; speedup 1.0000x reference)
//
#include <hip/hip_runtime.h>
#include <math.h>

// ---------------- problem constants ----------------
#define NB      32
#define NPTS    8192
#define TOTPTS  (NB * NPTS)        // 262144 points
#define TILE    512                // points per k_a block

typedef unsigned short u16;
typedef unsigned int   u32;
typedef __attribute__((ext_vector_type(8))) short bf16x8;  // 8 bf16 = 4 VGPR
typedef __attribute__((ext_vector_type(4))) float f32x4;   // MFMA C/D

__device__ __forceinline__ u16 f2bf(float f) {
    u32 u = __float_as_uint(f);
    u = (u + 0x7fffu + ((u >> 16) & 1u)) >> 16;   // RNE
    return (u16)u;
}
__device__ __forceinline__ u32 pk2(float a, float b) {
    return (u32)f2bf(a) | ((u32)f2bf(b) << 16);
}
__device__ __forceinline__ f32x4 MFMA(bf16x8 a, bf16x8 b, f32x4 c) {
    return __builtin_amdgcn_mfma_f32_16x16x32_bf16(a, b, c, 0, 0, 0);
}
template<int CTRL>
__device__ __forceinline__ float dpp_max(float v) {
    int t = __builtin_amdgcn_update_dpp(__float_as_int(v), __float_as_int(v),
                                        CTRL, 0xF, 0xF, false);
    return fmaxf(v, __int_as_float(t));
}
__device__ __forceinline__ float rowmax16(float v) {
    v = dpp_max<0xB1>(v);    // quad_perm xor1
    v = dpp_max<0x4E>(v);    // quad_perm xor2
    v = dpp_max<0x141>(v);   // row_half_mirror (xor4 on reduced)
    v = dpp_max<0x140>(v);   // row_mirror (xor8 on reduced)
    return v;
}
// async global->LDS, 16B per lane; LDS dest = wave-uniform base + lane*16
__device__ __forceinline__ void gload16(const void* g, void* l) {
    __builtin_amdgcn_global_load_lds(
        (const __attribute__((address_space(1))) unsigned int*)g,
        (__attribute__((address_space(3))) unsigned int*)l, 16, 0, 0);
}
#define VWAIT(n)  asm volatile("s_waitcnt vmcnt(" #n ")" ::: "memory")
#define SCHEDB()  __builtin_amdgcn_sched_barrier(0)
// Pin a W fragment into the AGPR half of the unified file. r5 evidence
// (VGPR_Count=104 with "+v" pin) says regalloc prefers AGPR for MFMA
// A-operands; "a" makes that explicit and kills any init copies/remat.
__device__ __forceinline__ void pinA(bf16x8& v) {
    asm volatile("" : "+a"(v));
}

// Fragment conventions (mfma_f32_16x16x32_bf16), verified rounds 2-5:
//   A: lane holds A[row=l&15][k=(l>>4)*8+j]  -> W[o][c] frag
//   B: lane holds B[k=(l>>4)*8+j][col=l&15]  -> H^T frag (col = point)
//   D: lane holds D[row=(l>>4)*4+r][col=l&15]
// Packed H: frag(pf,kf) at byte (pf*KF+kf)*1024 + lane*16.
// Packed W: frag(nf,kf) at byte (nf*KF+kf)*1024 + lane*16.

// ---------------- weight prepack (unchanged) ----------------
__global__ __launch_bounds__(256) void k_pack(const float* __restrict__ W2,
        const float* __restrict__ W3, const float* __restrict__ W4,
        const float* __restrict__ W5, u16* __restrict__ dst) {
    int idx = blockIdx.x * 256 + threadIdx.x;
    if (idx >= 720 * 64) return;
    int lane = idx & 63, fr = idx >> 6;
    const float* W; int C, frl;
    if (fr < 16)       { W = W2; C = 64;  frl = fr;       }
    else if (fr < 80)  { W = W3; C = 128; frl = fr - 16;  }
    else if (fr < 208) { W = W4; C = 256; frl = fr - 80;  }
    else               { W = W5; C = 256; frl = fr - 208; }
    int KF = C >> 5;
    int nf = frl / KF, kf = frl % KF;
    int o = nf * 16 + (lane & 15), c = kf * 32 + (lane >> 4) * 8;
    const float* s = W + (size_t)o * C + c;
    u32 out[4];
    #pragma unroll
    for (int j = 0; j < 4; ++j) out[j] = pk2(s[2 * j], s[2 * j + 1]);
    *(uint4*)((char*)dst + (size_t)idx * 16) = make_uint4(out[0], out[1], out[2], out[3]);
}

// ---------------- K_A: L1 (VALU 3->64) + L2 (MFMA 64->128), unchanged ----------------
__global__ __launch_bounds__(512) void k_a(const float* __restrict__ x,
        const float* __restrict__ W1, const float* __restrict__ b1,
        const u16* __restrict__ W2p, const float* __restrict__ b2,
        u16* __restrict__ H2p, int pt0) {
    __shared__ u16 H1[TILE * 64];
    const int tid = threadIdx.x, lane = tid & 63, w = tid >> 6;
    const int l15 = lane & 15, q = lane >> 4;
    const int t = blockIdx.x;
    const size_t ptbase = (size_t)pt0 + (size_t)t * TILE;
    const int b  = (int)(ptbase >> 13);
    const int nn = (int)(ptbase & 8191);

    const int myp = w * 64 + lane;
    const float* xb = x + (size_t)b * 3 * NPTS + nn + myp;
    const float x0 = xb[0], x1 = xb[NPTS], x2 = xb[2 * NPTS];
    {
        char* rowp = (char*)H1 + myp * 128;
        const int swz = (myp & 7) << 4;
        #pragma unroll
        for (int cb = 0; cb < 64; cb += 8) {
            u32 pkv[4];
            #pragma unroll
            for (int i = 0; i < 4; ++i) {
                int o0 = cb + 2 * i, o1 = o0 + 1;
                float a0 = fmaxf(b1[o0] + W1[o0*3]*x0 + W1[o0*3+1]*x1 + W1[o0*3+2]*x2, 0.f);
                float a1 = fmaxf(b1[o1] + W1[o1*3]*x0 + W1[o1*3+1]*x1 + W1[o1*3+2]*x2, 0.f);
                pkv[i] = pk2(a0, a1);
            }
            *(uint4*)(rowp + ((cb * 2) ^ swz)) = make_uint4(pkv[0], pkv[1], pkv[2], pkv[3]);
        }
    }
    __syncthreads();

    bf16x8 hb[2][4];
    #pragma unroll
    for (int kf = 0; kf < 2; ++kf)
        #pragma unroll
        for (int g = 0; g < 4; ++g) {
            int r2 = w * 64 + g * 16 + l15;
            hb[kf][g] = *(const bf16x8*)((const char*)H1 + r2 * 128 +
                                         ((kf * 64 + q * 16) ^ ((r2 & 7) << 4)));
        }
    const int qterm = ((q >> 1) * 16 + l15) * 16 + (q & 1) * 8;
    for (int nf = 0; nf < 8; ++nf) {
        f32x4 acc[4];
        f32x4 bv = *(const f32x4*)(b2 + nf * 16 + q * 4);
        #pragma unroll
        for (int g = 0; g < 4; ++g) acc[g] = bv;
        #pragma unroll
        for (int kf = 0; kf < 2; ++kf) {
            bf16x8 A = *(const bf16x8*)((const char*)W2p + (size_t)(nf * 2 + kf) * 1024 + lane * 16);
            #pragma unroll
            for (int g = 0; g < 4; ++g) acc[g] = MFMA(A, hb[kf][g], acc[g]);
        }
        #pragma unroll
        for (int g = 0; g < 4; ++g) {
            size_t pfc = (size_t)t * 32 + w * 4 + g;
            u32 d0 = pk2(fmaxf(acc[g][0], 0.f), fmaxf(acc[g][1], 0.f));
            u32 d1 = pk2(fmaxf(acc[g][2], 0.f), fmaxf(acc[g][3], 0.f));
            *(uint2*)((char*)H2p + (pfc * 4 + (nf >> 1)) * 1024 + (nf & 1) * 512 + qterm)
                = make_uint2(d0, d1);
        }
    }
}

// ---------------- K_MID v6: 4-wave blocks (2/CU), W in AGPRs, 3-buf DMA -------
// Block: 4 waves x 4 nf = all 16 nf (COUT=256); 16 pf per block, 2 pf/step.
template<int KF>
__global__ __launch_bounds__(256, 2) void k_mid(const u16* __restrict__ Hin,
        const u16* __restrict__ Wp, const float* __restrict__ bias,
        u16* __restrict__ Hout) {
    constexpr int BUFB  = 2 * KF * 1024;          // 8/16 KB per buffer
    constexpr int FPW   = KF / 2;                 // staged frags per wave (2/4)
    constexpr int STEPS = 8;                      // 16 pf / 2
    __shared__ char ldsB[3 * BUFB];               // 24/48 KB
    const int tid = threadIdx.x, lane = tid & 63, w = tid >> 6;
    const int l15 = lane & 15, q = lane >> 4;
    const int pfb = blockIdx.x * 16;
    const int qterm = ((q >> 1) * 16 + l15) * 16 + (q & 1) * 8;

    bf16x8 W[4][KF];                              // wave's 4 nf x KF, AGPR-pinned
    {
        const char* wb = (const char*)Wp + (size_t)(w * 4) * KF * 1024;
        #pragma unroll
        for (int nf = 0; nf < 4; ++nf)
            #pragma unroll
            for (int kf = 0; kf < KF; ++kf) {
                W[nf][kf] = *(const bf16x8*)(wb + (size_t)(nf * KF + kf) * 1024 + lane * 16);
                pinA(W[nf][kf]);
            }
    }
    f32x4 bv[4];
    #pragma unroll
    for (int nf = 0; nf < 4; ++nf)
        bv[nf] = *(const f32x4*)(bias + (w * 4 + nf) * 16 + q * 4);

    auto stage = [&](int t, int bsel) {           // 2 pf (= 2*KF frags), FPW per wave
        #pragma unroll
        for (int i = 0; i < FPW; ++i) {
            int idx = w * FPW + i;                // = p*KF + kf
            int p = idx / KF, kf = idx % KF;
            gload16((const char*)Hin + ((size_t)(pfb + t * 2 + p) * KF + kf) * 1024 + lane * 16,
                    ldsB + bsel * BUFB + idx * 1024 + lane * 16);
        }
    };
    stage(0, 0);
    stage(1, 1);
    int bufc = 0;
    for (int t = 0; t < STEPS; ++t) {
        // exact counted waits (stores count in vmcnt on CDNA!):
        //  t=0: after stage(0): FPW (stage1) in flight.
        //  steady: after stage(t): 8 stores + FPW (stage t+1) from iter t-1.
        //  last: after stage(S-1): 8 stores from iter S-2.
        if constexpr (KF == 8) {
            if (t == 0) VWAIT(4); else if (t < STEPS - 1) VWAIT(12); else VWAIT(8);
        } else {
            if (t == 0) VWAIT(2); else if (t < STEPS - 1) VWAIT(10); else VWAIT(8);
        }
        SCHEDB();
        __builtin_amdgcn_s_barrier();
        SCHEDB();
        const char* bp = ldsB + bufc * BUFB;
        #pragma unroll
        for (int p = 0; p < 2; ++p) {
            f32x4 acc[4];
            #pragma unroll
            for (int nf = 0; nf < 4; ++nf) acc[nf] = bv[nf];
            #pragma unroll
            for (int kf = 0; kf < KF; ++kf) {
                bf16x8 B = *(const bf16x8*)(bp + (size_t)(p * KF + kf) * 1024 + lane * 16);
                #pragma unroll
                for (int nf = 0; nf < 4; ++nf) acc[nf] = MFMA(W[nf][kf], B, acc[nf]);
            }
            const size_t pf = (size_t)pfb + t * 2 + p;
            #pragma unroll
            for (int nf = 0; nf < 4; ++nf) {                // ReLU + store (KF_out=8)
                int nfg = w * 4 + nf;
                u32 d0 = pk2(fmaxf(acc[nf][0], 0.f), fmaxf(acc[nf][1], 0.f));
                u32 d1 = pk2(fmaxf(acc[nf][2], 0.f), fmaxf(acc[nf][3], 0.f));
                *(uint2*)((char*)Hout + (pf * 8 + (nfg >> 1)) * 1024 + (nfg & 1) * 512 + qterm)
                    = make_uint2(d0, d1);
            }
        }
        // buf[(t+2)%3]'s last readers ran compute(t-1), all past barrier(t).
        if (t + 2 < STEPS) {
            int b2 = bufc + 2; if (b2 >= 3) b2 -= 3;
            stage(t + 2, b2);
        }
        ++bufc; if (bufc == 3) bufc = 0;
    }
}

// ---------------- K_L5 v6: 4-wave blocks (2/CU), ZSL=4, maxpool fused ---------
// Block: 4 waves x 4 nf = 16 nf = 256 z; 64 pf per block, 2 pf/step, 32 steps.
__global__ __launch_bounds__(256, 2) void k_l5(const u16* __restrict__ Hin,
        const u16* __restrict__ Wp, const float* __restrict__ b5,
        float* __restrict__ parts, int slot0) {
    constexpr int BUFB  = 16384;                  // 2 pf x 8 kf x 1KB
    constexpr int STEPS = 32;                     // 64 pf
    __shared__ char ldsB[3 * BUFB];               // 48 KB
    const int tid = threadIdx.x, lane = tid & 63, w = tid >> 6;
    const int l15 = lane & 15, q = lane >> 4;
    // sibling swizzle: 4 z-slices of one pgrp at bids {+0,+8,+16,+24} -> same
    // XCD under round-robin -> shared L2 for the pgrp's H4 tile.
    const int bid  = blockIdx.x;
    const int zsl  = (bid >> 3) & 3;
    const int pgrp = (bid & 7) | ((bid >> 5) << 3);
    const int pfb  = pgrp * 64;

    bf16x8 W[4][8];                               // 128 regs, AGPR-pinned
    {
        const char* wb = (const char*)Wp + (size_t)(zsl * 16 + w * 4) * 8 * 1024;
        #pragma unroll
        for (int nf = 0; nf < 4; ++nf)
            #pragma unroll
            for (int kf = 0; kf < 8; ++kf) {
                W[nf][kf] = *(const bf16x8*)(wb + (size_t)(nf * 8 + kf) * 1024 + lane * 16);
                pinA(W[nf][kf]);
            }
    }
    f32x4 vmax[4];
    #pragma unroll
    for (int nf = 0; nf < 4; ++nf)
        #pragma unroll
        for (int r = 0; r < 4; ++r) vmax[nf][r] = -3.402823466e38f;

    auto stage = [&](int t, int bsel) {           // 2 pf = 16 frags, 4 per wave
        #pragma unroll
        for (int i = 0; i < 4; ++i) {
            int idx = w * 4 + i;                  // = p*8 + kf
            int p = idx >> 3, kf = idx & 7;
            gload16((const char*)Hin + ((size_t)(pfb + t * 2 + p) * 8 + kf) * 1024 + lane * 16,
                    ldsB + bsel * BUFB + idx * 1024 + lane * 16);
        }
    };
    stage(0, 0);
    stage(1, 1);
    int bufc = 0;
    for (int t = 0; t < STEPS; ++t) {
        // no in-loop stores: clean counts. steady: stage(t+1)=4 in flight.
        if (t < STEPS - 1) VWAIT(4); else VWAIT(0);
        SCHEDB();
        __builtin_amdgcn_s_barrier();
        SCHEDB();
        const char* bp = ldsB + bufc * BUFB;
        #pragma unroll
        for (int p = 0; p < 2; ++p) {
            f32x4 acc[4];
            #pragma unroll
            for (int nf = 0; nf < 4; ++nf)
                #pragma unroll
                for (int r = 0; r < 4; ++r) acc[nf][r] = 0.f;
            #pragma unroll
            for (int kf = 0; kf < 8; ++kf) {
                bf16x8 B = *(const bf16x8*)(bp + (size_t)(p * 8 + kf) * 1024 + lane * 16);
                #pragma unroll
                for (int nf = 0; nf < 4; ++nf) acc[nf] = MFMA(W[nf][kf], B, acc[nf]);
            }
            #pragma unroll
            for (int nf = 0; nf < 4; ++nf)                 // deferred per-lane max
                #pragma unroll
                for (int r = 0; r < 4; ++r)
                    vmax[nf][r] = fmaxf(vmax[nf][r], acc[nf][r]);
        }
        if (t + 2 < STEPS) {
            int b2 = bufc + 2; if (b2 >= 3) b2 -= 3;
            stage(t + 2, b2);
        }
        ++bufc; if (bufc == 3) bufc = 0;
    }
    // one-time cross-lane reduce over the 16 point-columns, + bias, store.
    // lane (q,l15) keeps (nf,r) = (l15>>2, l15&3); z = zb + nf*16 + q*4 + r.
    const int zb = zsl * 256 + w * 64;
    float* dst = parts + (size_t)(slot0 + pgrp) * 1024 + zb;
    #pragma unroll
    for (int nf = 0; nf < 4; ++nf)
        #pragma unroll
        for (int r = 0; r < 4; ++r) {
            float m = rowmax16(vmax[nf][r]);
            if (l15 == nf * 4 + r) {
                int zi = nf * 16 + q * 4 + r;
                dst[zi] = m + b5[zb + zi];
            }
        }
}

// ---------------- final reduce: slot = 64-pf group; 8 slots per batch ---------
__global__ __launch_bounds__(256) void k_red(const float* __restrict__ parts,
                                             float* __restrict__ out) {
    int i = blockIdx.x * 256 + threadIdx.x;       // 32768
    int b = i >> 10, z = i & 1023;
    float m = -3.402823466e38f;
    #pragma unroll
    for (int s = 0; s < 8; ++s)
        m = fmaxf(m, parts[((size_t)b * 8 + s) * 1024 + z]);
    out[i] = m;
}

extern "C" void kernel_launch(void* const* d_in, const int* in_sizes, int n_in,
                              void* d_out, int out_size, void* d_ws, size_t ws_size,
                              hipStream_t stream) {
    const float* x  = (const float*)d_in[0];
    const float* W1 = (const float*)d_in[1]; const float* b1 = (const float*)d_in[2];
    const float* W2 = (const float*)d_in[3]; const float* b2 = (const float*)d_in[4];
    const float* W3 = (const float*)d_in[5]; const float* b3 = (const float*)d_in[6];
    const float* W4 = (const float*)d_in[7]; const float* b4 = (const float*)d_in[8];
    const float* W5 = (const float*)d_in[9]; const float* b5 = (const float*)d_in[10];

    u16* wsW = (u16*)d_ws;
    const u16* W2p = (const u16*)((char*)d_ws + 0);
    const u16* W3p = (const u16*)((char*)d_ws + 16 * 1024);
    const u16* W4p = (const u16*)((char*)d_ws + 80 * 1024);
    const u16* W5p = (const u16*)((char*)d_ws + 208 * 1024);
    float* parts   = (float*)((char*)d_ws + 786432);
    char* Hbase    = (char*)d_ws + 786432 + 16777216;

    int NCH = 1;
    while (NCH < 32) {
        size_t npc = (size_t)TOTPTS / NCH;
        if (786432 + 16777216 + npc * 1024 <= ws_size) break;
        NCH *= 2;
    }
    const size_t npts_c = (size_t)TOTPTS / NCH;
    char* HA = Hbase;
    char* HB = Hbase + npts_c * 512;

    k_pack<<<dim3(180), dim3(256), 0, stream>>>(W2, W3, W4, W5, wsW);

    const int ntc    = (int)(npts_c / TILE);       // k_a blocks per chunk
    const int npc_pf = (int)(npts_c / 16);         // point-frags per chunk
    for (int c = 0; c < NCH; ++c) {
        int pt0   = (int)(c * npts_c);
        int slot0 = (int)((c * npts_c) >> 10);     // 64-pf (1024-pt) groups
        k_a<<<dim3(ntc), dim3(512), 0, stream>>>(x, W1, b1, W2p, b2, (u16*)HB, pt0);
        k_mid<4><<<dim3(npc_pf / 16), dim3(256), 0, stream>>>((const u16*)HB, W3p, b3, (u16*)HA);
        k_mid<8><<<dim3(npc_pf / 16), dim3(256), 0, stream>>>((const u16*)HA, W4p, b4, (u16*)HB);
        k_l5<<<dim3(4 * (npc_pf / 64)), dim3(256), 0, stream>>>((const u16*)HB, W5p, b5, parts, slot0);
    }
    k_red<<<dim3(128), dim3(256), 0, stream>>>(parts, (float*)d_out);
}

// Round 7
// 164.372 us; speedup vs baseline: 1.5136x; 1.5136x over previous
//
#include <hip/hip_runtime.h>
#include <math.h>

// ---------------- problem constants ----------------
#define NB      32
#define NPTS    8192
#define TOTPTS  (NB * NPTS)        // 262144 points

typedef unsigned short u16;
typedef unsigned int   u32;
typedef __attribute__((ext_vector_type(8))) short bf16x8;  // 8 bf16 = 4 VGPR
typedef __attribute__((ext_vector_type(4))) float f32x4;   // MFMA C/D

__device__ __forceinline__ u16 f2bf(float f) {
    u32 u = __float_as_uint(f);
    u = (u + 0x7fffu + ((u >> 16) & 1u)) >> 16;   // RNE
    return (u16)u;
}
__device__ __forceinline__ u32 pk2(float a, float b) {
    return (u32)f2bf(a) | ((u32)f2bf(b) << 16);
}
__device__ __forceinline__ f32x4 MFMA(bf16x8 a, bf16x8 b, f32x4 c) {
    return __builtin_amdgcn_mfma_f32_16x16x32_bf16(a, b, c, 0, 0, 0);
}
template<int CTRL>
__device__ __forceinline__ float dpp_max(float v) {
    int t = __builtin_amdgcn_update_dpp(__float_as_int(v), __float_as_int(v),
                                        CTRL, 0xF, 0xF, false);
    return fmaxf(v, __int_as_float(t));
}
__device__ __forceinline__ float rowmax16(float v) {
    v = dpp_max<0xB1>(v);    // quad_perm xor1
    v = dpp_max<0x4E>(v);    // quad_perm xor2
    v = dpp_max<0x141>(v);   // row_half_mirror (xor4 on reduced)
    v = dpp_max<0x140>(v);   // row_mirror (xor8 on reduced)
    return v;
}
__device__ __forceinline__ void gload16(const void* g, void* l) {
    __builtin_amdgcn_global_load_lds(
        (const __attribute__((address_space(1))) unsigned int*)g,
        (__attribute__((address_space(3))) unsigned int*)l, 16, 0, 0);
}
template<int N> __device__ __forceinline__ void vwait() {
    if constexpr      (N == 0) asm volatile("s_waitcnt vmcnt(0)" ::: "memory");
    else if constexpr (N == 2) asm volatile("s_waitcnt vmcnt(2)" ::: "memory");
    else if constexpr (N == 4) asm volatile("s_waitcnt vmcnt(4)" ::: "memory");
    else                       asm volatile("s_waitcnt vmcnt(8)" ::: "memory");
}
__device__ __forceinline__ void pin(bf16x8& v) { asm volatile("" : "+v"(v)); }

// Fragment conventions (mfma_f32_16x16x32_bf16), verified rounds 2-6:
//   A: lane holds A[row=l&15][k=(l>>4)*8+j]  -> W[o][c] frag
//   B: lane holds B[k=(l>>4)*8+j][col=l&15]  -> H^T frag (col = point)
//   D: lane holds D[row=(l>>4)*4+r][col=l&15]
// Packed H: frag(pf,kf) at byte (pf*KF+kf)*1024 + lane*16.
// Packed W: frag(nf,kf) at byte (nf*KF+kf)*1024 + lane*16.

// ---------------- weight prepack (unchanged) ----------------
__global__ __launch_bounds__(256) void k_pack(const float* __restrict__ W2,
        const float* __restrict__ W3, const float* __restrict__ W4,
        const float* __restrict__ W5, u16* __restrict__ dst) {
    int idx = blockIdx.x * 256 + threadIdx.x;
    if (idx >= 720 * 64) return;
    int lane = idx & 63, fr = idx >> 6;
    const float* W; int C, frl;
    if (fr < 16)       { W = W2; C = 64;  frl = fr;       }
    else if (fr < 80)  { W = W3; C = 128; frl = fr - 16;  }
    else if (fr < 208) { W = W4; C = 256; frl = fr - 80;  }
    else               { W = W5; C = 256; frl = fr - 208; }
    int KF = C >> 5;
    int nf = frl / KF, kf = frl % KF;
    int o = nf * 16 + (lane & 15), c = kf * 32 + (lane >> 4) * 8;
    const float* s = W + (size_t)o * C + c;
    u32 out[4];
    #pragma unroll
    for (int j = 0; j < 4; ++j) out[j] = pk2(s[2 * j], s[2 * j + 1]);
    *(uint4*)((char*)dst + (size_t)idx * 16) = make_uint4(out[0], out[1], out[2], out[3]);
}

// ---------------- K_FUSE: L1+L2+L3+L4 in one kernel, LDS intermediates ------
// 8 waves, 128-pt tiles. region A: H1 (16K) then H3 (64K); region B: H2 (32K).
// Per tile: L1 (VALU) -> bar -> L2 (8x1nf) -> bar -> L3 (8x2nf) -> bar ->
//           L4 (8x2nf, store H4 frags to global) -> bar.
__global__ __launch_bounds__(512, 2) void k_fuse(const float* __restrict__ x,
        const float* __restrict__ W1, const float* __restrict__ b1,
        const u16* __restrict__ W2p, const float* __restrict__ b2,
        const u16* __restrict__ W3p, const float* __restrict__ b3,
        const u16* __restrict__ W4p, const float* __restrict__ b4,
        u16* __restrict__ H4, int pt0, int tpb) {
    __shared__ char regA[65536];               // H1 / H3
    __shared__ char regB[32768];               // H2
    const int tid = threadIdx.x, lane = tid & 63, w = tid >> 6;
    const int l15 = lane & 15, q = lane >> 4;
    const int qterm = ((q >> 1) * 16 + l15) * 16 + (q & 1) * 8;
    const int pl = tid & 127;                  // point-in-tile (L1)
    const int c4 = tid >> 7;                   // L1 channel quarter (wave-uniform)

    // persistent weight fragments (pinned; r4 lesson: prevent in-loop reload)
    bf16x8 W2r[2], W3r[2][4], W4r[2][8];
    #pragma unroll
    for (int kf = 0; kf < 2; ++kf) {
        W2r[kf] = *(const bf16x8*)((const char*)W2p + (size_t)(w * 2 + kf) * 1024 + lane * 16);
        pin(W2r[kf]);
    }
    #pragma unroll
    for (int n = 0; n < 2; ++n)
        #pragma unroll
        for (int kf = 0; kf < 4; ++kf) {
            W3r[n][kf] = *(const bf16x8*)((const char*)W3p +
                           (size_t)((w * 2 + n) * 4 + kf) * 1024 + lane * 16);
            pin(W3r[n][kf]);
        }
    #pragma unroll
    for (int n = 0; n < 2; ++n)
        #pragma unroll
        for (int kf = 0; kf < 8; ++kf) {
            W4r[n][kf] = *(const bf16x8*)((const char*)W4p +
                           (size_t)((w * 2 + n) * 8 + kf) * 1024 + lane * 16);
            pin(W4r[n][kf]);
        }
    const f32x4 b2v = *(const f32x4*)(b2 + w * 16 + q * 4);
    f32x4 b3v[2], b4v[2];
    #pragma unroll
    for (int n = 0; n < 2; ++n) {
        b3v[n] = *(const f32x4*)(b3 + (w * 2 + n) * 16 + q * 4);
        b4v[n] = *(const f32x4*)(b4 + (w * 2 + n) * 16 + q * 4);
    }

    const int tile0 = blockIdx.x * tpb;
    float x0, x1, x2;
    {   // first-tile x prefetch
        int ptg = pt0 + tile0 * 128 + pl;
        const float* xb = x + (size_t)(ptg >> 13) * 3 * NPTS + (ptg & 8191);
        x0 = xb[0]; x1 = xb[NPTS]; x2 = xb[2 * NPTS];
    }

    for (int it = 0; it < tpb; ++it) {
        const int tile = tile0 + it;
        // ---- L1: 3->64 (VALU), thread = (point pl, channel quarter c4) ----
        {
            u32 pk4[8];
            #pragma unroll
            for (int i = 0; i < 8; ++i) {
                int o0 = c4 * 16 + 2 * i, o1 = o0 + 1;
                float a0 = fmaxf(b1[o0] + W1[o0*3]*x0 + W1[o0*3+1]*x1 + W1[o0*3+2]*x2, 0.f);
                float a1 = fmaxf(b1[o1] + W1[o1*3]*x0 + W1[o1*3+1]*x1 + W1[o1*3+2]*x2, 0.f);
                pk4[i] = pk2(a0, a1);
            }
            char* rowp = regA + pl * 128;
            const int swz = (pl & 7) << 4;
            *(uint4*)(rowp + ((c4 * 32) ^ swz))      = make_uint4(pk4[0], pk4[1], pk4[2], pk4[3]);
            *(uint4*)(rowp + ((c4 * 32 + 16) ^ swz)) = make_uint4(pk4[4], pk4[5], pk4[6], pk4[7]);
        }
        __syncthreads();
        // ---- L2: 64->128, wave w owns nf=w; read H1 (swz rows), write H2 ----
        #pragma unroll
        for (int pf = 0; pf < 8; ++pf) {
            const int r2 = pf * 16 + l15;
            const char* rb = regA + r2 * 128;
            const int rsw = (r2 & 7) << 4;
            bf16x8 B0 = *(const bf16x8*)(rb + ((q * 16) ^ rsw));
            bf16x8 B1 = *(const bf16x8*)(rb + ((64 + q * 16) ^ rsw));
            f32x4 a = b2v;
            a = MFMA(W2r[0], B0, a);
            a = MFMA(W2r[1], B1, a);
            u32 d0 = pk2(fmaxf(a[0], 0.f), fmaxf(a[1], 0.f));
            u32 d1 = pk2(fmaxf(a[2], 0.f), fmaxf(a[3], 0.f));
            *(uint2*)(regB + (pf * 4 + (w >> 1)) * 1024 + (w & 1) * 512 + qterm)
                = make_uint2(d0, d1);
        }
        __syncthreads();
        // ---- L3: 128->256, wave w owns nf=2w,2w+1; read H2, write H3 -------
        #pragma unroll
        for (int pf = 0; pf < 8; ++pf) {
            bf16x8 B[4];
            #pragma unroll
            for (int kf = 0; kf < 4; ++kf)
                B[kf] = *(const bf16x8*)(regB + (pf * 4 + kf) * 1024 + lane * 16);
            f32x4 a0 = b3v[0], a1 = b3v[1];
            #pragma unroll
            for (int kf = 0; kf < 4; ++kf) {
                a0 = MFMA(W3r[0][kf], B[kf], a0);
                a1 = MFMA(W3r[1][kf], B[kf], a1);
            }
            char* db = regA + (pf * 8 + w) * 1024;
            *(uint2*)(db + qterm)       = make_uint2(pk2(fmaxf(a0[0],0.f), fmaxf(a0[1],0.f)),
                                                     pk2(fmaxf(a0[2],0.f), fmaxf(a0[3],0.f)));
            *(uint2*)(db + 512 + qterm) = make_uint2(pk2(fmaxf(a1[0],0.f), fmaxf(a1[1],0.f)),
                                                     pk2(fmaxf(a1[2],0.f), fmaxf(a1[3],0.f)));
        }
        __syncthreads();
        // ---- L4: 256->256, wave w owns nf=2w,2w+1; read H3, store H4 global -
        #pragma unroll
        for (int pf = 0; pf < 8; ++pf) {
            bf16x8 B[8];
            #pragma unroll
            for (int kf = 0; kf < 8; ++kf)
                B[kf] = *(const bf16x8*)(regA + (pf * 8 + kf) * 1024 + lane * 16);
            f32x4 a0 = b4v[0], a1 = b4v[1];
            #pragma unroll
            for (int kf = 0; kf < 8; ++kf) {
                a0 = MFMA(W4r[0][kf], B[kf], a0);
                a1 = MFMA(W4r[1][kf], B[kf], a1);
            }
            char* db = (char*)H4 + ((size_t)(tile * 8 + pf) * 8 + w) * 1024;
            *(uint2*)(db + qterm)       = make_uint2(pk2(fmaxf(a0[0],0.f), fmaxf(a0[1],0.f)),
                                                     pk2(fmaxf(a0[2],0.f), fmaxf(a0[3],0.f)));
            *(uint2*)(db + 512 + qterm) = make_uint2(pk2(fmaxf(a1[0],0.f), fmaxf(a1[1],0.f)),
                                                     pk2(fmaxf(a1[2],0.f), fmaxf(a1[3],0.f)));
        }
        if (it + 1 < tpb) {                    // next-tile x prefetch
            int ptg = pt0 + (tile + 1) * 128 + pl;
            const float* xb = x + (size_t)(ptg >> 13) * 3 * NPTS + (ptg & 8191);
            x0 = xb[0]; x1 = xb[NPTS]; x2 = xb[2 * NPTS];
        }
        __syncthreads();                       // protect regA before next L1
    }
}

// ---------------- K_L5: r4 version verbatim (best measured: 52.8 us) ---------
// Block: 8 waves = 32 nf (zsl half of 1024 z); 64 pf per block, 2 pf/step.
__global__ __launch_bounds__(512, 2) void k_l5(const u16* __restrict__ Hin,
        const u16* __restrict__ Wp, const float* __restrict__ b5,
        float* __restrict__ parts, int slot0) {
    constexpr int BUFB = 16384;                // 2 pf x 8 kf x 1KB
    constexpr int STEPS = 32;                  // 64 pf
    __shared__ char ldsB[3 * BUFB];            // 48 KB
    const int tid = threadIdx.x, lane = tid & 63, w = tid >> 6;
    const int l15 = lane & 15, q = lane >> 4;
    const int zsl = blockIdx.x & 1, pgrp = blockIdx.x >> 1;
    const int pfb = pgrp * 64;

    bf16x8 W[4][8];
    {
        const char* wb = (const char*)Wp + (size_t)(zsl * 32 + w * 4) * 8 * 1024;
        #pragma unroll
        for (int nf = 0; nf < 4; ++nf)
            #pragma unroll
            for (int kf = 0; kf < 8; ++kf)
                W[nf][kf] = *(const bf16x8*)(wb + (size_t)(nf * 8 + kf) * 1024 + lane * 16);
    }
    f32x4 vmax[4];
    #pragma unroll
    for (int nf = 0; nf < 4; ++nf)
        #pragma unroll
        for (int r = 0; r < 4; ++r) vmax[nf][r] = -3.402823466e38f;

    auto stage = [&](int t, int bsel) {
        const char* g = (const char*)Hin + ((size_t)(pfb + t * 2) * 8) * 1024
                        + w * 2048 + lane * 16;
        char* l = ldsB + bsel * BUFB + w * 2048;
        gload16(g, l);
        gload16(g + 1024, l + 1024);
    };
    stage(0, 0);
    stage(1, 1);
    int bufc = 0;
    for (int t = 0; t < STEPS; ++t) {
        if (t + 1 < STEPS) vwait<2>(); else vwait<0>();
        __builtin_amdgcn_sched_barrier(0);
        __builtin_amdgcn_s_barrier();
        const char* bp = ldsB + bufc * BUFB;
        #pragma unroll
        for (int p = 0; p < 2; ++p) {
            f32x4 acc[4];
            #pragma unroll
            for (int nf = 0; nf < 4; ++nf)
                #pragma unroll
                for (int r = 0; r < 4; ++r) acc[nf][r] = 0.f;
            #pragma unroll
            for (int kf = 0; kf < 8; ++kf) {
                bf16x8 B = *(const bf16x8*)(bp + (size_t)(p * 8 + kf) * 1024 + lane * 16);
                #pragma unroll
                for (int nf = 0; nf < 4; ++nf) acc[nf] = MFMA(W[nf][kf], B, acc[nf]);
            }
            #pragma unroll
            for (int nf = 0; nf < 4; ++nf)
                #pragma unroll
                for (int r = 0; r < 4; ++r)
                    vmax[nf][r] = fmaxf(vmax[nf][r], acc[nf][r]);
        }
        if (t + 2 < STEPS) {
            int b2 = bufc + 2; if (b2 >= 3) b2 -= 3;
            stage(t + 2, b2);
        }
        ++bufc; if (bufc == 3) bufc = 0;
    }
    const int zb = zsl * 512 + w * 64;
    float* dst = parts + (size_t)(slot0 + pgrp) * 1024 + zb;
    #pragma unroll
    for (int nf = 0; nf < 4; ++nf)
        #pragma unroll
        for (int r = 0; r < 4; ++r) {
            float m = rowmax16(vmax[nf][r]);
            if (l15 == nf * 4 + r) {
                int zi = nf * 16 + q * 4 + r;
                dst[zi] = m + b5[zb + zi];
            }
        }
}

// ---------------- final reduce: slot = 64-pf group; 8 slots per batch ---------
__global__ __launch_bounds__(256) void k_red(const float* __restrict__ parts,
                                             float* __restrict__ out) {
    int i = blockIdx.x * 256 + threadIdx.x;    // 32768
    int b = i >> 10, z = i & 1023;
    float m = -3.402823466e38f;
    #pragma unroll
    for (int s = 0; s < 8; ++s)
        m = fmaxf(m, parts[((size_t)b * 8 + s) * 1024 + z]);
    out[i] = m;
}

extern "C" void kernel_launch(void* const* d_in, const int* in_sizes, int n_in,
                              void* d_out, int out_size, void* d_ws, size_t ws_size,
                              hipStream_t stream) {
    const float* x  = (const float*)d_in[0];
    const float* W1 = (const float*)d_in[1]; const float* b1 = (const float*)d_in[2];
    const float* W2 = (const float*)d_in[3]; const float* b2 = (const float*)d_in[4];
    const float* W3 = (const float*)d_in[5]; const float* b3 = (const float*)d_in[6];
    const float* W4 = (const float*)d_in[7]; const float* b4 = (const float*)d_in[8];
    const float* W5 = (const float*)d_in[9]; const float* b5 = (const float*)d_in[10];

    u16* wsW = (u16*)d_ws;
    const u16* W2p = (const u16*)((char*)d_ws + 0);
    const u16* W3p = (const u16*)((char*)d_ws + 16 * 1024);
    const u16* W4p = (const u16*)((char*)d_ws + 80 * 1024);
    const u16* W5p = (const u16*)((char*)d_ws + 208 * 1024);
    float* parts   = (float*)((char*)d_ws + 786432);           // 256 slots x 4KB = 1 MB
    char* Hbase    = (char*)d_ws + 786432 + 2097152;

    int NCH = 1;
    while (NCH < 32) {
        size_t npc = (size_t)TOTPTS / NCH;
        if (786432 + 2097152 + npc * 512 <= ws_size) break;
        NCH *= 2;
    }
    const size_t npts_c = (size_t)TOTPTS / NCH;
    char* HB = Hbase;                           // H4 chunk buffer (512 B/pt)

    k_pack<<<dim3(180), dim3(256), 0, stream>>>(W2, W3, W4, W5, wsW);

    const int ntiles = (int)(npts_c / 128);     // k_fuse tiles per chunk
    const int nblk   = (ntiles >= 256) ? 256 : ntiles;
    const int tpb    = ntiles / nblk;
    const int npc_pf = (int)(npts_c / 16);      // point-frags per chunk
    for (int c = 0; c < NCH; ++c) {
        int pt0   = (int)(c * npts_c);
        int slot0 = (int)((c * npts_c) >> 10);  // 1024-pt groups
        k_fuse<<<dim3(nblk), dim3(512), 0, stream>>>(
            x, W1, b1, W2p, b2, W3p, b3, W4p, b4, (u16*)HB, pt0, tpb);
        k_l5<<<dim3(2 * (npc_pf / 64)), dim3(512), 0, stream>>>(
            (const u16*)HB, W5p, b5, parts, slot0);
    }
    k_red<<<dim3(128), dim3(256), 0, stream>>>(parts, (float*)d_out);
}